// Round 16
// baseline (1953.111 us; speedup 1.0000x reference)
//
#include <hip/hip_runtime.h>

typedef _Float16 half8   __attribute__((ext_vector_type(8)));
typedef _Float16 half2_t __attribute__((ext_vector_type(2)));
typedef float    floatx4 __attribute__((ext_vector_type(4)));
typedef unsigned int uintx4 __attribute__((ext_vector_type(4)));
typedef unsigned int uint32;

__device__ __forceinline__ float sigm(float v) { return 1.0f / (1.0f + __expf(-v)); }
__device__ __forceinline__ float tanh_(float v) { float e = __expf(2.0f * v); return (e - 1.0f) / (e + 1.0f); }

__device__ __forceinline__ int dot4(uint32 a, uint32 b, int c) {
#if __has_builtin(__builtin_amdgcn_sdot4)
  return __builtin_amdgcn_sdot4((int)a, (int)b, c, false);
#else
  int r = c;
  r += (int)(char)(a)       * (int)(char)(b);
  r += (int)(char)(a >> 8)  * (int)(char)(b >> 8);
  r += (int)(char)(a >> 16) * (int)(char)(b >> 16);
  r += (int)(char)(a >> 24) * (int)(char)(b >> 24);
  return r;
#endif
}

__device__ __forceinline__ uint32 pack_rte(float a, float b) {
  half2_t h; h[0] = (_Float16)a; h[1] = (_Float16)b;
  return __builtin_bit_cast(uint32, h);
}

// ---------------- pack W_ih: f32 -> f16 pairs, flat ----------------
__global__ __launch_bounds__(256) void pack_wih(const float* __restrict__ wih, uint32* __restrict__ wihd) {
  int p = blockIdx.x * 256 + threadIdx.x;   // 1048576 pairs
  wihd[p] = pack_rte(wih[2 * p], wih[2 * p + 1]);
}

// ---------------- pack W_hh: f32 -> i8, layout [k][qt][qi][row], scale 2032 ----------------
__global__ __launch_bounds__(256) void pack_whh8(const float* __restrict__ whh, uintx4* __restrict__ wq8) {
  int p = blockIdx.x * 256 + threadIdx.x;   // 65536 quads
  int row = p & 1023, qi = (p >> 10) & 3, qt = (p >> 12) & 3, kk = p >> 14;
  const float* src = whh + ((size_t)(kk * 1024 + row)) * 256 + qt * 64 + qi * 16;
  uint32 dw[4];
#pragma unroll
  for (int d = 0; d < 4; ++d) {
    uint32 v = 0;
#pragma unroll
    for (int e = 0; e < 4; ++e) {
      int q = (int)rintf(src[d * 4 + e] * 2032.0f);
      q = q > 127 ? 127 : (q < -127 ? -127 : q);
      v |= ((uint32)(q & 0xff)) << (8 * e);
    }
    dw[d] = v;
  }
  wq8[p] = (uintx4){dw[0], dw[1], dw[2], dw[3]};
}

// ---------------- pack ALL x slices: xs[chunk][k][R=b*32+ct][512] f16 ----------------
__global__ __launch_bounds__(256) void pack_x_all(const float* __restrict__ x, uint32* __restrict__ xsd) {
  for (long p = (long)blockIdx.x * 256 + threadIdx.x; p < 33554432L; p += 2097152L) {
    int chunk = (int)(p >> 21);
    int r = (int)(p & 2097151);
    int k  = r >> 19;
    int R  = (r >> 8) & 2047;   // R = b*32 + ct
    int pc = r & 255;
    int b = R >> 5, ct = R & 31;
    int t = chunk * 32 + ct;
    int sk = (k * 1024) / 6;    // 0,170,341,512
    const float* src = x + ((size_t)t * 64 + b) * 1024 + sk + pc * 2;
    xsd[p] = pack_rte(src[0], src[1]);
  }
}

// ---------------- phase 1 (ALL chunks): xg16 = xs @ Wih^T + bias via f16 MFMA ----------------
__global__ __launch_bounds__(256) void gemm_all(const _Float16* __restrict__ xs,
                                                const _Float16* __restrict__ wih16,
                                                const float* __restrict__ bih,
                                                const float* __restrict__ bhh,
                                                _Float16* __restrict__ xg) {
  __shared__ _Float16 SL[18432];
  const int tid = threadIdx.x;
  const int bid = blockIdx.x;
  const int chunk = bid >> 9;
  const int b9 = bid & 511;
  const int nt = b9 & 7, mt = (b9 >> 3) & 15, kb = b9 >> 7;
  const int l = tid & 63;
  const int wid = tid >> 6;
  const int wm = wid >> 1, wn = wid & 1;
  const int lr = l & 15, lk = l >> 4;

  floatx4 acc[4][4] = {};
  const _Float16* xsk = xs + ((size_t)(chunk * 4 + kb) << 20);
  const _Float16* wk  = wih16 + ((size_t)kb << 19);

  for (int kt = 0; kt < 8; ++kt) {
    const int K0 = kt * 64;
    half8 av[4], bv[4];
#pragma unroll
    for (int q = 0; q < 4; ++q) {
      int s = q * 256 + tid;
      int row = s >> 3, c8 = s & 7;
      av[q] = *(const half8*)(xsk + (size_t)(mt * 128 + row) * 512 + K0 + c8 * 8);
      bv[q] = *(const half8*)(wk  + (size_t)(nt * 128 + row) * 512 + K0 + c8 * 8);
    }
#pragma unroll
    for (int q = 0; q < 4; ++q) {
      int s = q * 256 + tid;
      int row = s >> 3, c8 = s & 7;
      *(half8*)&SL[row * 72 + c8 * 8]        = av[q];
      *(half8*)&SL[9216 + row * 72 + c8 * 8] = bv[q];
    }
    __syncthreads();
#pragma unroll
    for (int ks = 0; ks < 2; ++ks) {
      half8 af[4], bf[4];
#pragma unroll
      for (int fm = 0; fm < 4; ++fm)
        af[fm] = *(const half8*)&SL[(wm * 64 + fm * 16 + lr) * 72 + (ks * 4 + lk) * 8];
#pragma unroll
      for (int fn = 0; fn < 4; ++fn)
        bf[fn] = *(const half8*)&SL[9216 + (wn * 64 + fn * 16 + lr) * 72 + (ks * 4 + lk) * 8];
#pragma unroll
      for (int fm = 0; fm < 4; ++fm)
#pragma unroll
        for (int fn = 0; fn < 4; ++fn)
          acc[fm][fn] = __builtin_amdgcn_mfma_f32_16x16x32_f16(af[fm], bf[fn], acc[fm][fn], 0, 0, 0);
    }
    __syncthreads();
  }
  float bias[4];
#pragma unroll
  for (int fn = 0; fn < 4; ++fn) {
    int g = nt * 128 + wn * 64 + fn * 16 + lr;
    bias[fn] = bih[kb * 1024 + g] + bhh[kb * 1024 + g];
  }
#pragma unroll
  for (int fm = 0; fm < 4; ++fm)
#pragma unroll
    for (int fn = 0; fn < 4; ++fn) {
      int colb = wn * 64 + fn * 16 + lr;
#pragma unroll
      for (int r = 0; r < 4; ++r) {
        int rowb = wm * 64 + fm * 16 + lk * 4 + r;
        SL[rowb * 128 + colb] = (_Float16)(acc[fm][fn][r] + bias[fn]);
      }
    }
  __syncthreads();
#pragma unroll
  for (int q = 0; q < 8; ++q) {
    int s = q * 256 + tid;
    int row = s >> 4, c16 = s & 15;
    int R = mt * 128 + row;
    size_t off = ((size_t)(kb * 64 + (R >> 5)) * 512 + chunk * 32 + (R & 31)) * 1024 + nt * 128 + c16 * 8;
    *(uintx4*)(xg + off) = *(const uintx4*)&SL[row * 128 + c16 * 8];
  }
}

// ---------------- phase 2: ONE launch, 256 blocks x 256 threads, 512 steps ----------------
// Weight residence the compiler cannot undo: 34 quads/thread in LDS (136 KB, lane-consecutive
// conflict-free), 16 quads (gate 0) in named regs (streams from L2 if evicted - bounded cost),
// 14 quads (gate 3 tail) streamed from L2 (56 KB/step vs r15's 256 KB/step = the 922us wall).
// Raw s_barrier + explicit lgkmcnt(0) per step (NOT __syncthreads) so slab prefetch survives
// barriers; vmcnt(0) only at 4-step slab boundaries (data 4 steps old -> free drain).
// LDS dw: [0,128) h8 [2][256] i8 | [128,4224) slab [2][4][1024] f16 | [4224,39040) wl [34][256] quads.
// Total 156,160 B.
__global__ __launch_bounds__(256, 1)
void lstm_all(const _Float16* __restrict__ xg,
              const uintx4* __restrict__ wq8,
              const float* __restrict__ h0,
              const float* __restrict__ c0,
              float* __restrict__ out) {
  extern __shared__ uint32 lds[];
  unsigned char* h8   = (unsigned char*)lds;            // [2][256] i8
  _Float16*      slab = (_Float16*)(lds + 128);         // [2][4][1024]
  uintx4*        wl4  = (uintx4*)(lds + 4224);          // [34][256]
  const int j = threadIdx.x;
  const int k = blockIdx.x >> 6, b = blockIdx.x & 63;

  const uintx4* wk = wq8 + ((size_t)k << 14);
  // gate 0: 16 quads -> named registers
#define LR(i) uintx4 R##i = wk[((i) >> 2) * 4096 + ((i) & 3) * 1024 + j];
  LR(0) LR(1) LR(2) LR(3) LR(4) LR(5) LR(6) LR(7)
  LR(8) LR(9) LR(10) LR(11) LR(12) LR(13) LR(14) LR(15)
#undef LR
  // gates 1,2 (all 16 quads each) + gate 3 quads 0,1 -> LDS
#pragma unroll
  for (int g = 1; g <= 2; ++g)
#pragma unroll
    for (int i = 0; i < 16; ++i)
      wl4[((g - 1) * 16 + i) * 256 + j] = wk[(i >> 2) * 4096 + (i & 3) * 1024 + g * 256 + j];
  wl4[32 * 256 + j] = wk[768 + j];
  wl4[33 * 256 + j] = wk[1024 + 768 + j];
  const uintx4* w3 = wk + 768 + j;   // gate 3 streamed quads: w3[(i>>2)*4096 + (i&3)*1024]

  const int gi = b * 1024 + k * 256 + j;
  float cst = c0[gi];
  float hn_prev = h0[gi];
  {
    int q = (int)rintf(hn_prev * (127.0f / 8.0f));   // h0 unbounded -> scale 8
    q = q > 127 ? 127 : (q < -127 ? -127 : q);
    h8[j] = (unsigned char)(q & 0xff);
  }

  const _Float16* xgp = xg + ((size_t)(k * 64 + b) << 19);   // 512 steps * 1024 gates
  // prologue: stage slab halves 0 (steps 0-3) and 1 (steps 4-7)
#pragma unroll
  for (int q = 0; q < 2; ++q) {
    __builtin_amdgcn_global_load_lds(
        (const __attribute__((address_space(1))) void*)(xgp + q * 2048 + j * 8),
        (__attribute__((address_space(3))) void*)(lds + 128 + q * 1024 + j * 4), 16, 0, 0);
    __builtin_amdgcn_global_load_lds(
        (const __attribute__((address_space(1))) void*)(xgp + 4096 + q * 2048 + j * 8),
        (__attribute__((address_space(3))) void*)(lds + 128 + 2048 + q * 1024 + j * 4), 16, 0, 0);
  }
  asm volatile("s_waitcnt vmcnt(0) lgkmcnt(0)" ::: "memory");
  __builtin_amdgcn_sched_barrier(0);
  __builtin_amdgcn_s_barrier();

  const float DS1 = 0.0625f / 16129.0f;   // (1/16 / 127) * (1 / 127)
  const float DS8 = 8.0f * DS1;

#define MQ(W, H, d) { d = dot4(W[0], H[0], d); d = dot4(W[1], H[1], d); \
                      d = dot4(W[2], H[2], d); d = dot4(W[3], H[3], d); }
#define SI_L(i) { uintx4 hq = hp[i]; \
    MQ(R##i, hq, d0) \
    { uintx4 w = wl4[(i) * 256 + j];        MQ(w, hq, d1) } \
    { uintx4 w = wl4[(16 + (i)) * 256 + j]; MQ(w, hq, d2) } \
    { uintx4 w = wl4[(32 + (i)) * 256 + j]; MQ(w, hq, d3) } }
#define SI_G(i) { uintx4 hq = hp[i]; \
    MQ(R##i, hq, d0) \
    { uintx4 w = wl4[(i) * 256 + j];        MQ(w, hq, d1) } \
    { uintx4 w = wl4[(16 + (i)) * 256 + j]; MQ(w, hq, d2) } \
    { uintx4 w = w3[((i) >> 2) * 4096 + ((i) & 3) * 1024]; MQ(w, hq, d3) } }

#pragma unroll 1
  for (int t = 0; t < 512; ++t) {
    if ((t & 3) == 0 && t) {
      asm volatile("s_waitcnt vmcnt(0)" ::: "memory");   // slab half (issued t-4) + store acks
      __builtin_amdgcn_sched_barrier(0);
      if (t + 4 < 512) {
        const int nh = (((t >> 2) & 1) ^ 1);
#pragma unroll
        for (int q = 0; q < 2; ++q)
          __builtin_amdgcn_global_load_lds(
              (const __attribute__((address_space(1))) void*)(xgp + (size_t)(t + 4) * 1024 + q * 2048 + j * 8),
              (__attribute__((address_space(3))) void*)(lds + 128 + nh * 2048 + q * 1024 + j * 4), 16, 0, 0);
      }
    }
    const uintx4* hp = (const uintx4*)(h8 + (t & 1) * 256);
    const _Float16* sl = slab + ((t >> 2) & 1) * 4096 + (t & 3) * 1024;

    int d0 = 0, d1 = 0, d2 = 0, d3 = 0;
    SI_L(0) SI_L(1)
    SI_G(2) SI_G(3) SI_G(4) SI_G(5) SI_G(6) SI_G(7)
    SI_G(8) SI_G(9) SI_G(10) SI_G(11) SI_G(12) SI_G(13) SI_G(14) SI_G(15)

    float xi = (float)sl[j];
    float xf = (float)sl[256 + j];
    float xgv = (float)sl[512 + j];
    float xo = (float)sl[768 + j];

    float dsc = (t == 0) ? DS8 : DS1;
    float iv = (float)d0 * dsc + xi;
    float fv = (float)d1 * dsc + xf;
    float gv = (float)d2 * dsc + xgv;
    float ov = (float)d3 * dsc + xo;
    float cn = sigm(fv) * cst + sigm(iv) * tanh_(gv);
    float hn = sigm(ov) * tanh_(cn);
    cst = cn; hn_prev = hn;
    out[((size_t)t * 64 + b) * 1024 + k * 256 + j] = hn;       // fire-and-forget
    {
      int q = (int)rintf(hn * 127.0f);   // |hn| < 1
      h8[((t & 1) ^ 1) * 256 + j] = (unsigned char)(q & 0xff);
    }
    asm volatile("s_waitcnt lgkmcnt(0)" ::: "memory");
    __builtin_amdgcn_sched_barrier(0);
    __builtin_amdgcn_s_barrier();
  }
#undef MQ
#undef SI_L
#undef SI_G

  out[33554432 + gi] = hn_prev;          // new_h
  out[33554432 + 65536 + gi] = cst;      // new_c
}

extern "C" void kernel_launch(void* const* d_in, const int* in_sizes, int n_in,
                              void* d_out, int out_size, void* d_ws, size_t ws_size,
                              hipStream_t stream) {
  const float* x   = (const float*)d_in[0];
  const float* h0  = (const float*)d_in[1];
  const float* c0  = (const float*)d_in[2];
  const float* Wih = (const float*)d_in[3];
  const float* Whh = (const float*)d_in[4];
  const float* bih = (const float*)d_in[5];
  const float* bhh = (const float*)d_in[6];
  float* out = (float*)d_out;
  char* ws = (char*)d_ws;

  // ws usage: 407,896,064 B (r14 fills showed ws >= ~514 MB)
  _Float16* xg16  = (_Float16*)ws;                   // 268,435,456 B  [k][b][t 512][gate]
  _Float16* xs    = (_Float16*)(ws + 268435456L);    // 134,217,728 B  [chunk][k][R][512]
  _Float16* wih16 = (_Float16*)(ws + 402653184L);    //   4,194,304 B
  uintx4*   wq8   = (uintx4*)(ws + 406847488L);      //   1,048,576 B  (i8 weights)

  hipFuncSetAttribute((const void*)lstm_all, hipFuncAttributeMaxDynamicSharedMemorySize, 156160);

  pack_wih<<<4096, 256, 0, stream>>>(Wih, (uint32*)wih16);
  pack_whh8<<<256, 256, 0, stream>>>(Whh, wq8);
  pack_x_all<<<8192, 256, 0, stream>>>(x, (uint32*)xs);
  gemm_all<<<8192, 256, 0, stream>>>(xs, wih16, bih, bhh, xg16);
  lstm_all<<<256, 256, 156160, stream>>>(xg16, wq8, h0, c0, out);
}

// Round 17
// 1286.620 us; speedup vs baseline: 1.5180x; 1.5180x over previous
//
#include <hip/hip_runtime.h>

typedef _Float16 half8   __attribute__((ext_vector_type(8)));
typedef _Float16 half2_t __attribute__((ext_vector_type(2)));
typedef float    floatx4 __attribute__((ext_vector_type(4)));
typedef unsigned int uintx4 __attribute__((ext_vector_type(4)));
typedef unsigned int uint32;

__device__ __forceinline__ float sigm(float v) { return 1.0f / (1.0f + __expf(-v)); }
__device__ __forceinline__ float tanh_(float v) { float e = __expf(2.0f * v); return (e - 1.0f) / (e + 1.0f); }

__device__ __forceinline__ int dot4(uint32 a, uint32 b, int c) {
#if __has_builtin(__builtin_amdgcn_sdot4)
  return __builtin_amdgcn_sdot4((int)a, (int)b, c, false);
#else
  int r = c;
  r += (int)(char)(a)       * (int)(char)(b);
  r += (int)(char)(a >> 8)  * (int)(char)(b >> 8);
  r += (int)(char)(a >> 16) * (int)(char)(b >> 16);
  r += (int)(char)(a >> 24) * (int)(char)(b >> 24);
  return r;
#endif
}

__device__ __forceinline__ uint32 pack_rte(float a, float b) {
  half2_t h; h[0] = (_Float16)a; h[1] = (_Float16)b;
  return __builtin_bit_cast(uint32, h);
}

// ---------------- pack W_ih: f32 -> f16 pairs, flat ----------------
__global__ __launch_bounds__(256) void pack_wih(const float* __restrict__ wih, uint32* __restrict__ wihd) {
  int p = blockIdx.x * 256 + threadIdx.x;   // 1048576 pairs
  wihd[p] = pack_rte(wih[2 * p], wih[2 * p + 1]);
}

// ---------------- pack W_hh: f32 -> i8, layout [k][qt][qi][row], scale 2032 ----------------
__global__ __launch_bounds__(256) void pack_whh8(const float* __restrict__ whh, uintx4* __restrict__ wq8) {
  int p = blockIdx.x * 256 + threadIdx.x;   // 65536 quads
  int row = p & 1023, qi = (p >> 10) & 3, qt = (p >> 12) & 3, kk = p >> 14;
  const float* src = whh + ((size_t)(kk * 1024 + row)) * 256 + qt * 64 + qi * 16;
  uint32 dw[4];
#pragma unroll
  for (int d = 0; d < 4; ++d) {
    uint32 v = 0;
#pragma unroll
    for (int e = 0; e < 4; ++e) {
      int q = (int)rintf(src[d * 4 + e] * 2032.0f);
      q = q > 127 ? 127 : (q < -127 ? -127 : q);
      v |= ((uint32)(q & 0xff)) << (8 * e);
    }
    dw[d] = v;
  }
  wq8[p] = (uintx4){dw[0], dw[1], dw[2], dw[3]};
}

// ---------------- pack ALL x slices: xs[chunk][k][R=b*32+ct][512] f16 ----------------
__global__ __launch_bounds__(256) void pack_x_all(const float* __restrict__ x, uint32* __restrict__ xsd) {
  for (long p = (long)blockIdx.x * 256 + threadIdx.x; p < 33554432L; p += 2097152L) {
    int chunk = (int)(p >> 21);
    int r = (int)(p & 2097151);
    int k  = r >> 19;
    int R  = (r >> 8) & 2047;   // R = b*32 + ct
    int pc = r & 255;
    int b = R >> 5, ct = R & 31;
    int t = chunk * 32 + ct;
    int sk = (k * 1024) / 6;    // 0,170,341,512
    const float* src = x + ((size_t)t * 64 + b) * 1024 + sk + pc * 2;
    xsd[p] = pack_rte(src[0], src[1]);
  }
}

// ---------------- phase 1 (ALL chunks): xg16 = xs @ Wih^T + bias via f16 MFMA ----------------
__global__ __launch_bounds__(256) void gemm_all(const _Float16* __restrict__ xs,
                                                const _Float16* __restrict__ wih16,
                                                const float* __restrict__ bih,
                                                const float* __restrict__ bhh,
                                                _Float16* __restrict__ xg) {
  __shared__ _Float16 SL[18432];
  const int tid = threadIdx.x;
  const int bid = blockIdx.x;
  const int chunk = bid >> 9;
  const int b9 = bid & 511;
  const int nt = b9 & 7, mt = (b9 >> 3) & 15, kb = b9 >> 7;
  const int l = tid & 63;
  const int wid = tid >> 6;
  const int wm = wid >> 1, wn = wid & 1;
  const int lr = l & 15, lk = l >> 4;

  floatx4 acc[4][4] = {};
  const _Float16* xsk = xs + ((size_t)(chunk * 4 + kb) << 20);
  const _Float16* wk  = wih16 + ((size_t)kb << 19);

  for (int kt = 0; kt < 8; ++kt) {
    const int K0 = kt * 64;
    half8 av[4], bv[4];
#pragma unroll
    for (int q = 0; q < 4; ++q) {
      int s = q * 256 + tid;
      int row = s >> 3, c8 = s & 7;
      av[q] = *(const half8*)(xsk + (size_t)(mt * 128 + row) * 512 + K0 + c8 * 8);
      bv[q] = *(const half8*)(wk  + (size_t)(nt * 128 + row) * 512 + K0 + c8 * 8);
    }
#pragma unroll
    for (int q = 0; q < 4; ++q) {
      int s = q * 256 + tid;
      int row = s >> 3, c8 = s & 7;
      *(half8*)&SL[row * 72 + c8 * 8]        = av[q];
      *(half8*)&SL[9216 + row * 72 + c8 * 8] = bv[q];
    }
    __syncthreads();
#pragma unroll
    for (int ks = 0; ks < 2; ++ks) {
      half8 af[4], bf[4];
#pragma unroll
      for (int fm = 0; fm < 4; ++fm)
        af[fm] = *(const half8*)&SL[(wm * 64 + fm * 16 + lr) * 72 + (ks * 4 + lk) * 8];
#pragma unroll
      for (int fn = 0; fn < 4; ++fn)
        bf[fn] = *(const half8*)&SL[9216 + (wn * 64 + fn * 16 + lr) * 72 + (ks * 4 + lk) * 8];
#pragma unroll
      for (int fm = 0; fm < 4; ++fm)
#pragma unroll
        for (int fn = 0; fn < 4; ++fn)
          acc[fm][fn] = __builtin_amdgcn_mfma_f32_16x16x32_f16(af[fm], bf[fn], acc[fm][fn], 0, 0, 0);
    }
    __syncthreads();
  }
  float bias[4];
#pragma unroll
  for (int fn = 0; fn < 4; ++fn) {
    int g = nt * 128 + wn * 64 + fn * 16 + lr;
    bias[fn] = bih[kb * 1024 + g] + bhh[kb * 1024 + g];
  }
#pragma unroll
  for (int fm = 0; fm < 4; ++fm)
#pragma unroll
    for (int fn = 0; fn < 4; ++fn) {
      int colb = wn * 64 + fn * 16 + lr;
#pragma unroll
      for (int r = 0; r < 4; ++r) {
        int rowb = wm * 64 + fm * 16 + lk * 4 + r;
        SL[rowb * 128 + colb] = (_Float16)(acc[fm][fn][r] + bias[fn]);
      }
    }
  __syncthreads();
#pragma unroll
  for (int q = 0; q < 8; ++q) {
    int s = q * 256 + tid;
    int row = s >> 4, c16 = s & 15;
    int R = mt * 128 + row;
    size_t off = ((size_t)(kb * 64 + (R >> 5)) * 512 + chunk * 32 + (R & 31)) * 1024 + nt * 128 + c16 * 8;
    *(uintx4*)(xg + off) = *(const uintx4*)&SL[row * 128 + c16 * 8];
  }
}

// ---------------- phase 2: ONE launch, 256 blocks x 256 threads, 512 steps ----------------
// r15 structure (compiler-managed __syncthreads loop, no sched_barrier/raw barriers -- r16's
// pinning broke pipelining) + HALF the weights moved to LDS: gates 1,2 in wl4 (128 KB,
// lane-consecutive conflict-free), gates 0,3 streamed from L2 (128 KB/step, was 256 KB/step
// = r15's 922us L2-BW wall). Slab (8 steps) + hist (8 steps) in LDS; one vmcnt drain per
// 8 steps. LDS dw: [0,128) h8 [2][256] i8 | [128,4224) slab [8][1024] f16 |
// [4224,5248) hist [8][256] f16 | [5248,38016) wl4 [32][256] quads. Total 152,064 B.
__global__ __launch_bounds__(256, 1)
void lstm_all(const _Float16* __restrict__ xg,
              const uintx4* __restrict__ wq8,
              const float* __restrict__ h0,
              const float* __restrict__ c0,
              float* __restrict__ out) {
  extern __shared__ uint32 lds[];
  unsigned char* h8   = (unsigned char*)lds;            // [2][256] i8
  const _Float16* slab = (const _Float16*)(lds + 128);  // [8][1024]
  _Float16*      hist = (_Float16*)(lds + 4224);        // [8][256]
  uintx4*        wl4  = (uintx4*)(lds + 5248);          // [32][256]
  const int j = threadIdx.x;
  const int k = blockIdx.x >> 6, b = blockIdx.x & 63;

  const uintx4* wk = wq8 + ((size_t)k << 14);
  // gates 1,2 -> LDS (32 quads/thread, lane-consecutive)
#pragma unroll
  for (int i = 0; i < 16; ++i) {
    wl4[i * 256 + j]        = wk[(i >> 2) * 4096 + (i & 3) * 1024 + 256 + j];
    wl4[(16 + i) * 256 + j] = wk[(i >> 2) * 4096 + (i & 3) * 1024 + 512 + j];
  }
  // gates 0,3 streamed each step
  const uintx4* w0s = wk + j;          // quad i at [(i>>2)*4096 + (i&3)*1024]
  const uintx4* w3s = wk + 768 + j;

  const int gi = b * 1024 + k * 256 + j;
  float cst = c0[gi];
  float hn_prev = h0[gi];
  {
    int q = (int)rintf(hn_prev * (127.0f / 8.0f));   // h0 unbounded -> scale 8
    q = q > 127 ? 127 : (q < -127 ? -127 : q);
    h8[j] = (unsigned char)(q & 0xff);
  }

  const float DS1 = 0.0625f / 16129.0f;   // (1/16 / 127) * (1 / 127)
  const float DS8 = 8.0f * DS1;

  const _Float16* xgp = xg + ((size_t)(k * 64 + b) << 19);   // 512 steps * 1024 gates

#define MQ(W, H, d) { d = dot4(W[0], H[0], d); d = dot4(W[1], H[1], d); \
                      d = dot4(W[2], H[2], d); d = dot4(W[3], H[3], d); }
#define STEPI(i) { uintx4 hq = hp[i]; \
    { uintx4 w = w0s[((i) >> 2) * 4096 + ((i) & 3) * 1024]; MQ(w, hq, d0) } \
    { uintx4 w = wl4[(i) * 256 + j];        MQ(w, hq, d1) } \
    { uintx4 w = wl4[(16 + (i)) * 256 + j]; MQ(w, hq, d2) } \
    { uintx4 w = w3s[((i) >> 2) * 4096 + ((i) & 3) * 1024]; MQ(w, hq, d3) } }

#pragma unroll 1
  for (int t = 0; t < 512; ++t) {
    if ((t & 7) == 0) {
      if (t) {  // dump previous 8 steps' h (coalesced f32); stores drain at next boundary
        int tb = t - 8;
#pragma unroll
        for (int q = 0; q < 8; ++q)
          out[((size_t)(tb + q) * 64 + b) * 1024 + k * 256 + j] = (float)hist[q * 256 + j];
      }
      // stage 8 steps of gates: 16 KB, linear global -> linear LDS
#pragma unroll
      for (int q = 0; q < 4; ++q)
        __builtin_amdgcn_global_load_lds(
            (const __attribute__((address_space(1))) void*)(xgp + (size_t)t * 1024 + q * 2048 + j * 8),
            (__attribute__((address_space(3))) void*)(lds + 128 + q * 1024 + j * 4), 16, 0, 0);
      asm volatile("s_waitcnt vmcnt(0)" ::: "memory");
      __syncthreads();
    }

    const int cur = t & 1;
    const uintx4* hp = (const uintx4*)(h8 + cur * 256);
    int d0 = 0, d1 = 0, d2 = 0, d3 = 0;
    STEPI(0)  STEPI(1)  STEPI(2)  STEPI(3)  STEPI(4)  STEPI(5)  STEPI(6)  STEPI(7)
    STEPI(8)  STEPI(9)  STEPI(10) STEPI(11) STEPI(12) STEPI(13) STEPI(14) STEPI(15)

    const int ts = (t & 7) * 1024;
    float xi = (float)slab[ts + j];
    float xf = (float)slab[ts + 256 + j];
    float xgv = (float)slab[ts + 512 + j];
    float xo = (float)slab[ts + 768 + j];

    float dsc = (t == 0) ? DS8 : DS1;
    float iv = (float)d0 * dsc + xi;
    float fv = (float)d1 * dsc + xf;
    float gv = (float)d2 * dsc + xgv;
    float ov = (float)d3 * dsc + xo;
    float cn = sigm(fv) * cst + sigm(iv) * tanh_(gv);
    float hn = sigm(ov) * tanh_(cn);
    cst = cn; hn_prev = hn;
    hist[(t & 7) * 256 + j] = (_Float16)hn;
    {
      int q = (int)rintf(hn * 127.0f);   // |hn| < 1
      h8[(cur ^ 1) * 256 + j] = (unsigned char)(q & 0xff);
    }
    __syncthreads();
  }
#undef MQ
#undef STEPI

  // dump last 8 steps
#pragma unroll
  for (int q = 0; q < 8; ++q)
    out[((size_t)(504 + q) * 64 + b) * 1024 + k * 256 + j] = (float)hist[q * 256 + j];
  out[33554432 + gi] = hn_prev;          // new_h
  out[33554432 + 65536 + gi] = cst;      // new_c
}

extern "C" void kernel_launch(void* const* d_in, const int* in_sizes, int n_in,
                              void* d_out, int out_size, void* d_ws, size_t ws_size,
                              hipStream_t stream) {
  const float* x   = (const float*)d_in[0];
  const float* h0  = (const float*)d_in[1];
  const float* c0  = (const float*)d_in[2];
  const float* Wih = (const float*)d_in[3];
  const float* Whh = (const float*)d_in[4];
  const float* bih = (const float*)d_in[5];
  const float* bhh = (const float*)d_in[6];
  float* out = (float*)d_out;
  char* ws = (char*)d_ws;

  // ws usage: 407,896,064 B (r14 fills showed ws >= ~514 MB)
  _Float16* xg16  = (_Float16*)ws;                   // 268,435,456 B  [k][b][t 512][gate]
  _Float16* xs    = (_Float16*)(ws + 268435456L);    // 134,217,728 B  [chunk][k][R][512]
  _Float16* wih16 = (_Float16*)(ws + 402653184L);    //   4,194,304 B
  uintx4*   wq8   = (uintx4*)(ws + 406847488L);      //   1,048,576 B  (i8 weights)

  hipFuncSetAttribute((const void*)lstm_all, hipFuncAttributeMaxDynamicSharedMemorySize, 152064);

  pack_wih<<<4096, 256, 0, stream>>>(Wih, (uint32*)wih16);
  pack_whh8<<<256, 256, 0, stream>>>(Whh, wq8);
  pack_x_all<<<8192, 256, 0, stream>>>(x, (uint32*)xs);
  gemm_all<<<8192, 256, 0, stream>>>(xs, wih16, bih, bhh, xg16);
  lstm_all<<<256, 256, 152064, stream>>>(xg16, wq8, h0, c0, out);
}

// Round 18
// 954.763 us; speedup vs baseline: 2.0457x; 1.3476x over previous
//
#include <hip/hip_runtime.h>

typedef _Float16 half8   __attribute__((ext_vector_type(8)));
typedef _Float16 half2_t __attribute__((ext_vector_type(2)));
typedef float    floatx4 __attribute__((ext_vector_type(4)));
typedef unsigned int uintx4 __attribute__((ext_vector_type(4)));
typedef unsigned int uint32;

__device__ __forceinline__ float sigm(float v) { return 1.0f / (1.0f + __expf(-v)); }
__device__ __forceinline__ float tanh_(float v) { float e = __expf(2.0f * v); return (e - 1.0f) / (e + 1.0f); }

__device__ __forceinline__ int dot4(uint32 a, uint32 b, int c) {
#if __has_builtin(__builtin_amdgcn_sdot4)
  return __builtin_amdgcn_sdot4((int)a, (int)b, c, false);
#else
  int r = c;
  r += (int)(char)(a)       * (int)(char)(b);
  r += (int)(char)(a >> 8)  * (int)(char)(b >> 8);
  r += (int)(char)(a >> 16) * (int)(char)(b >> 16);
  r += (int)(char)(a >> 24) * (int)(char)(b >> 24);
  return r;
#endif
}

__device__ __forceinline__ uint32 pack_rte(float a, float b) {
  half2_t h; h[0] = (_Float16)a; h[1] = (_Float16)b;
  return __builtin_bit_cast(uint32, h);
}

// ---------------- pack W_ih: f32 -> f16 pairs, flat ----------------
__global__ __launch_bounds__(256) void pack_wih(const float* __restrict__ wih, uint32* __restrict__ wihd) {
  int p = blockIdx.x * 256 + threadIdx.x;   // 1048576 pairs
  wihd[p] = pack_rte(wih[2 * p], wih[2 * p + 1]);
}

// ---------------- pack W_hh: f32 -> i8, layout [k][qt][qi][row], scale 2032 ----------------
__global__ __launch_bounds__(256) void pack_whh8(const float* __restrict__ whh, uintx4* __restrict__ wq8) {
  int p = blockIdx.x * 256 + threadIdx.x;   // 65536 quads
  int row = p & 1023, qi = (p >> 10) & 3, qt = (p >> 12) & 3, kk = p >> 14;
  const float* src = whh + ((size_t)(kk * 1024 + row)) * 256 + qt * 64 + qi * 16;
  uint32 dw[4];
#pragma unroll
  for (int d = 0; d < 4; ++d) {
    uint32 v = 0;
#pragma unroll
    for (int e = 0; e < 4; ++e) {
      int q = (int)rintf(src[d * 4 + e] * 2032.0f);
      q = q > 127 ? 127 : (q < -127 ? -127 : q);
      v |= ((uint32)(q & 0xff)) << (8 * e);
    }
    dw[d] = v;
  }
  wq8[p] = (uintx4){dw[0], dw[1], dw[2], dw[3]};
}

// ---------------- pack ALL x slices: xs[chunk][k][R=b*32+ct][512] f16 ----------------
__global__ __launch_bounds__(256) void pack_x_all(const float* __restrict__ x, uint32* __restrict__ xsd) {
  for (long p = (long)blockIdx.x * 256 + threadIdx.x; p < 33554432L; p += 2097152L) {
    int chunk = (int)(p >> 21);
    int r = (int)(p & 2097151);
    int k  = r >> 19;
    int R  = (r >> 8) & 2047;   // R = b*32 + ct
    int pc = r & 255;
    int b = R >> 5, ct = R & 31;
    int t = chunk * 32 + ct;
    int sk = (k * 1024) / 6;    // 0,170,341,512
    const float* src = x + ((size_t)t * 64 + b) * 1024 + sk + pc * 2;
    xsd[p] = pack_rte(src[0], src[1]);
  }
}

// ---------------- phase 1 (ALL chunks): xg16 = xs @ Wih^T + bias via f16 MFMA ----------------
__global__ __launch_bounds__(256) void gemm_all(const _Float16* __restrict__ xs,
                                                const _Float16* __restrict__ wih16,
                                                const float* __restrict__ bih,
                                                const float* __restrict__ bhh,
                                                _Float16* __restrict__ xg) {
  __shared__ _Float16 SL[18432];
  const int tid = threadIdx.x;
  const int bid = blockIdx.x;
  const int chunk = bid >> 9;
  const int b9 = bid & 511;
  const int nt = b9 & 7, mt = (b9 >> 3) & 15, kb = b9 >> 7;
  const int l = tid & 63;
  const int wid = tid >> 6;
  const int wm = wid >> 1, wn = wid & 1;
  const int lr = l & 15, lk = l >> 4;

  floatx4 acc[4][4] = {};
  const _Float16* xsk = xs + ((size_t)(chunk * 4 + kb) << 20);
  const _Float16* wk  = wih16 + ((size_t)kb << 19);

  for (int kt = 0; kt < 8; ++kt) {
    const int K0 = kt * 64;
    half8 av[4], bv[4];
#pragma unroll
    for (int q = 0; q < 4; ++q) {
      int s = q * 256 + tid;
      int row = s >> 3, c8 = s & 7;
      av[q] = *(const half8*)(xsk + (size_t)(mt * 128 + row) * 512 + K0 + c8 * 8);
      bv[q] = *(const half8*)(wk  + (size_t)(nt * 128 + row) * 512 + K0 + c8 * 8);
    }
#pragma unroll
    for (int q = 0; q < 4; ++q) {
      int s = q * 256 + tid;
      int row = s >> 3, c8 = s & 7;
      *(half8*)&SL[row * 72 + c8 * 8]        = av[q];
      *(half8*)&SL[9216 + row * 72 + c8 * 8] = bv[q];
    }
    __syncthreads();
#pragma unroll
    for (int ks = 0; ks < 2; ++ks) {
      half8 af[4], bf[4];
#pragma unroll
      for (int fm = 0; fm < 4; ++fm)
        af[fm] = *(const half8*)&SL[(wm * 64 + fm * 16 + lr) * 72 + (ks * 4 + lk) * 8];
#pragma unroll
      for (int fn = 0; fn < 4; ++fn)
        bf[fn] = *(const half8*)&SL[9216 + (wn * 64 + fn * 16 + lr) * 72 + (ks * 4 + lk) * 8];
#pragma unroll
      for (int fm = 0; fm < 4; ++fm)
#pragma unroll
        for (int fn = 0; fn < 4; ++fn)
          acc[fm][fn] = __builtin_amdgcn_mfma_f32_16x16x32_f16(af[fm], bf[fn], acc[fm][fn], 0, 0, 0);
    }
    __syncthreads();
  }
  float bias[4];
#pragma unroll
  for (int fn = 0; fn < 4; ++fn) {
    int g = nt * 128 + wn * 64 + fn * 16 + lr;
    bias[fn] = bih[kb * 1024 + g] + bhh[kb * 1024 + g];
  }
#pragma unroll
  for (int fm = 0; fm < 4; ++fm)
#pragma unroll
    for (int fn = 0; fn < 4; ++fn) {
      int colb = wn * 64 + fn * 16 + lr;
#pragma unroll
      for (int r = 0; r < 4; ++r) {
        int rowb = wm * 64 + fm * 16 + lk * 4 + r;
        SL[rowb * 128 + colb] = (_Float16)(acc[fm][fn][r] + bias[fn]);
      }
    }
  __syncthreads();
#pragma unroll
  for (int q = 0; q < 8; ++q) {
    int s = q * 256 + tid;
    int row = s >> 4, c16 = s & 15;
    int R = mt * 128 + row;
    size_t off = ((size_t)(kb * 64 + (R >> 5)) * 512 + chunk * 32 + (R & 31)) * 1024 + nt * 128 + c16 * 8;
    *(uintx4*)(xg + off) = *(const uintx4*)&SL[row * 128 + c16 * 8];
  }
}

// ---------------- phase 2: ONE launch, 256 blocks x 512 threads, 512 steps ----------------
// K-SPLIT-2 for overlap: thread (j = tid>>1, s = tid&1) owns all 4 gate rows of hidden unit j,
// K-half [s*128, s*128+128). 2 waves/SIMD (the r17 fix: at 1 wave/SIMD the L2/LDS/VALU phases
// ran in SERIES = 5000cy/step; 2 waves let them overlap). Weight split balances the pipes:
// gate 3 -> LDS (8 quads/thread, 64 KB, lane-consecutive conflict-free, ~1550cy/step);
// gates 0,1,2 -> 24 named quads (96 VGPR; if the allocator keeps them: zero stream; if it
// streams: 96 KB/step unique ~1710cy aggregate -- acceptable either way). h-reads halve to
// 8 quads/thread. Gate halves summed by one shfl_xor(1) per gate (lane pairs, same wave).
// Plain __syncthreads loop (no sched_barrier/raw barriers -- r16 lesson).
// LDS dw: [0,128) h8 [2][256] i8 | [128,4224) slab [8][1024] f16 | [4224,5248) hist [8][256] f16
//         | [5248,21632) wl4 [8][512] quads.  Total 86,528 B.
__global__ __launch_bounds__(512, 2)
void lstm_all(const _Float16* __restrict__ xg,
              const uintx4* __restrict__ wq8,
              const float* __restrict__ h0,
              const float* __restrict__ c0,
              float* __restrict__ out) {
  extern __shared__ uint32 lds[];
  unsigned char* h8   = (unsigned char*)lds;            // [2][256] i8
  const _Float16* slab = (const _Float16*)(lds + 128);  // [8][1024]
  _Float16*      hist = (_Float16*)(lds + 4224);        // [8][256]
  uintx4*        wl4  = (uintx4*)(lds + 5248);          // [8][512]
  const int tid = threadIdx.x;
  const int j = tid >> 1, s = tid & 1;
  const int k = blockIdx.x >> 6, b = blockIdx.x & 63;

  const uintx4* wk = wq8 + ((size_t)k << 14);
  // gates 0,1,2 K-half s: 24 named quads (quad i covers K = s*128 + i*16)
#define LQ(g, i) uintx4 S##g##_##i = wk[(2 * s + ((i) >> 2)) * 4096 + ((i) & 3) * 1024 + (g) * 256 + j];
  LQ(0,0) LQ(0,1) LQ(0,2) LQ(0,3) LQ(0,4) LQ(0,5) LQ(0,6) LQ(0,7)
  LQ(1,0) LQ(1,1) LQ(1,2) LQ(1,3) LQ(1,4) LQ(1,5) LQ(1,6) LQ(1,7)
  LQ(2,0) LQ(2,1) LQ(2,2) LQ(2,3) LQ(2,4) LQ(2,5) LQ(2,6) LQ(2,7)
#undef LQ
  // gate 3 K-half s -> LDS, lane-consecutive
#pragma unroll
  for (int i = 0; i < 8; ++i)
    wl4[i * 512 + tid] = wk[(2 * s + (i >> 2)) * 4096 + (i & 3) * 1024 + 768 + j];

  const int gi = b * 1024 + k * 256 + j;
  float cst = c0[gi];
  float hn_prev = h0[gi];
  if (!s) {
    int q = (int)rintf(hn_prev * (127.0f / 8.0f));   // h0 unbounded -> scale 8
    q = q > 127 ? 127 : (q < -127 ? -127 : q);
    h8[j] = (unsigned char)(q & 0xff);
  }

  const float DS1 = 0.0625f / 16129.0f;   // (1/16 / 127) * (1 / 127)
  const float DS8 = 8.0f * DS1;

  const _Float16* xgp = xg + ((size_t)(k * 64 + b) << 19);   // 512 steps * 1024 gates

#define MQ(W, H, d) { d = dot4(W[0], H[0], d); d = dot4(W[1], H[1], d); \
                      d = dot4(W[2], H[2], d); d = dot4(W[3], H[3], d); }
#define STEPI(i) { uintx4 hq = hp4[s * 8 + (i)]; \
    MQ(S0_##i, hq, d0) MQ(S1_##i, hq, d1) MQ(S2_##i, hq, d2) \
    { uintx4 w = wl4[(i) * 512 + tid]; MQ(w, hq, d3) } }

#pragma unroll 1
  for (int t = 0; t < 512; ++t) {
    if ((t & 7) == 0) {
      if (t) {  // dump previous 8 steps' h (2048 f16, 4 per thread)
        int tb = t - 8;
#pragma unroll
        for (int q = 0; q < 4; ++q) {
          int idx = q * 512 + tid;
          int ct = idx >> 8, jj = idx & 255;
          out[((size_t)(tb + ct) * 64 + b) * 1024 + k * 256 + jj] = (float)hist[idx];
        }
      }
      // stage 8 steps of gates: 16 KB, linear global -> linear LDS
#pragma unroll
      for (int q = 0; q < 2; ++q)
        __builtin_amdgcn_global_load_lds(
            (const __attribute__((address_space(1))) void*)(xgp + (size_t)t * 1024 + q * 4096 + tid * 8),
            (__attribute__((address_space(3))) void*)(lds + 128 + q * 2048 + tid * 4), 16, 0, 0);
      asm volatile("s_waitcnt vmcnt(0)" ::: "memory");
      __syncthreads();
    }

    const uintx4* hp4 = (const uintx4*)(h8 + (t & 1) * 256);
    int d0 = 0, d1 = 0, d2 = 0, d3 = 0;
    STEPI(0) STEPI(1) STEPI(2) STEPI(3) STEPI(4) STEPI(5) STEPI(6) STEPI(7)

    // sum the two K-halves across the lane pair (both lanes end with full sums)
    d0 += __shfl_xor(d0, 1, 64);
    d1 += __shfl_xor(d1, 1, 64);
    d2 += __shfl_xor(d2, 1, 64);
    d3 += __shfl_xor(d3, 1, 64);

    const int ts = (t & 7) * 1024;
    float xi = (float)slab[ts + j];
    float xf = (float)slab[ts + 256 + j];
    float xgv = (float)slab[ts + 512 + j];
    float xo = (float)slab[ts + 768 + j];

    float dsc = (t == 0) ? DS8 : DS1;
    float iv = (float)d0 * dsc + xi;
    float fv = (float)d1 * dsc + xf;
    float gv = (float)d2 * dsc + xgv;
    float ov = (float)d3 * dsc + xo;
    float cn = sigm(fv) * cst + sigm(iv) * tanh_(gv);
    float hn = sigm(ov) * tanh_(cn);
    cst = cn; hn_prev = hn;
    if (!s) {
      hist[(t & 7) * 256 + j] = (_Float16)hn;
      int q = (int)rintf(hn * 127.0f);   // |hn| < 1
      h8[((t & 1) ^ 1) * 256 + j] = (unsigned char)(q & 0xff);
    }
    __syncthreads();
  }
#undef MQ
#undef STEPI

  // dump last 8 steps
#pragma unroll
  for (int q = 0; q < 4; ++q) {
    int idx = q * 512 + tid;
    int ct = idx >> 8, jj = idx & 255;
    out[((size_t)(504 + ct) * 64 + b) * 1024 + k * 256 + jj] = (float)hist[idx];
  }
  if (!s) {
    out[33554432 + gi] = hn_prev;          // new_h
    out[33554432 + 65536 + gi] = cst;      // new_c
  }
}

extern "C" void kernel_launch(void* const* d_in, const int* in_sizes, int n_in,
                              void* d_out, int out_size, void* d_ws, size_t ws_size,
                              hipStream_t stream) {
  const float* x   = (const float*)d_in[0];
  const float* h0  = (const float*)d_in[1];
  const float* c0  = (const float*)d_in[2];
  const float* Wih = (const float*)d_in[3];
  const float* Whh = (const float*)d_in[4];
  const float* bih = (const float*)d_in[5];
  const float* bhh = (const float*)d_in[6];
  float* out = (float*)d_out;
  char* ws = (char*)d_ws;

  // ws usage: 407,896,064 B (r14 fills showed ws >= ~514 MB)
  _Float16* xg16  = (_Float16*)ws;                   // 268,435,456 B  [k][b][t 512][gate]
  _Float16* xs    = (_Float16*)(ws + 268435456L);    // 134,217,728 B  [chunk][k][R][512]
  _Float16* wih16 = (_Float16*)(ws + 402653184L);    //   4,194,304 B
  uintx4*   wq8   = (uintx4*)(ws + 406847488L);      //   1,048,576 B  (i8 weights)

  hipFuncSetAttribute((const void*)lstm_all, hipFuncAttributeMaxDynamicSharedMemorySize, 86528);

  pack_wih<<<4096, 256, 0, stream>>>(Wih, (uint32*)wih16);
  pack_whh8<<<256, 256, 0, stream>>>(Whh, wq8);
  pack_x_all<<<8192, 256, 0, stream>>>(x, (uint32*)xs);
  gemm_all<<<8192, 256, 0, stream>>>(xs, wih16, bih, bhh, xg16);
  lstm_all<<<256, 512, 86528, stream>>>(xg16, wq8, h0, c0, out);
}